// Round 1
// 1126.674 us; speedup vs baseline: 1.0993x; 1.0993x over previous
//
#include <hip/hip_runtime.h>
#include <hip/hip_bf16.h>
#include <stdint.h>

#define SEQ      4096
#define BATCH    4
#define HIDDEN   2048
#define CHANNELS 4096
#define MTOT     (BATCH*SEQ)   // 16384

typedef __bf16 bf16;
typedef __bf16 bf16x8 __attribute__((ext_vector_type(8)));
typedef float  f32x4  __attribute__((ext_vector_type(4)));

// async 16B global->LDS (wave-uniform base + lane*16 on LDS side)
#define GLDS16(g, l) __builtin_amdgcn_global_load_lds(                      \
    (const __attribute__((address_space(1))) void*)(g),                     \
    (__attribute__((address_space(3))) void*)(l), 16, 0, 0)

union B8 { uint4 v; bf16 h[8]; };

// ---------------------------------------------------------------------------
// fp32 -> bf16 cast, 8 elems/thread
// ---------------------------------------------------------------------------
__global__ __launch_bounds__(256)
void cast_f32_to_bf16(const float* __restrict__ in, bf16* __restrict__ out) {
    const long long i = (long long)blockIdx.x * 256 + threadIdx.x;
    const float4 a = ((const float4*)in)[2 * i];
    const float4 b = ((const float4*)in)[2 * i + 1];
    B8 o;
    o.h[0] = (bf16)a.x; o.h[1] = (bf16)a.y; o.h[2] = (bf16)a.z; o.h[3] = (bf16)a.w;
    o.h[4] = (bf16)b.x; o.h[5] = (bf16)b.y; o.h[6] = (bf16)b.z; o.h[7] = (bf16)b.w;
    *(uint4*)(out + 8 * i) = o.v;
}

// ---------------------------------------------------------------------------
// NT GEMM, 256x256 tile, BK=64, 512 thr (8 waves: 2M x 4N), 8-phase schedule.
// C[m][n] = sum_k A[m][k]*B[n][k] + bias[n].
//
// LDS: 8 half-tile slots of 16 KB (128 rows x 64 bf16), [buf][kind]:
//   kind 0 = A rows [0,128), 1 = B rows [0,128), 2 = A rows [128,256),
//   kind 3 = B rows [128,256).  Stage s: tile s>>2, kind s&3, buf (s>>2)&1.
// Chunk swizzle (proven, 0 conflicts): LDS slot q holds global chunk
// q^(row&7); GLDS dest stays lane-linear, source is pre-swizzled.
//
// Each wave (wr,wc) owns rows {mh*128 + wr*64 + [0,64)} x cols
// {nh*128 + wc*32 + [0,32)} for mh,nh in {0,1} -> phase q=(mh,nh) reads
// exactly one A-half + one B-half, releasing slots phase-by-phase.
// Schedule per phase: 12 ds_read_b128; lgkmcnt(0); barrier; stage 1
// half-tile (issued 7 phases ahead of its use); setprio(1); 16 MFMA;
// setprio(0); [vmcnt(6) once per K-tile]; barrier.  vmcnt never drained
// to 0 in steady state -> 3 half-tiles stay in flight across barriers.
// ---------------------------------------------------------------------------
template <typename OutT, int N, int K>
__global__ __launch_bounds__(512, 2)
void gemm256_bt_bias(const bf16* __restrict__ A, const bf16* __restrict__ B,
                     const float* __restrict__ bias, OutT* __restrict__ C) {
    constexpr int NT = K / 64;           // K-tiles
    __shared__ bf16 lds[8][128 * 64];    // 128 KiB

    const int tid  = threadIdx.x;
    const int lane = tid & 63;
    const int wave = tid >> 6;
    const int wr   = wave >> 2;          // 0..1
    const int wc   = wave & 3;           // 0..3
    const int quad = lane >> 4;          // 0..3
    const int lrow = lane & 15;          // 0..15

    // XCD-chunked bijective swizzle (nwg % 8 == 0), M fastest -> each XCD
    // keeps its B-panel(s) L2-resident while streaming A.
    const int nwg = gridDim.x;
    const int bid = blockIdx.x;
    const int swz = (bid & 7) * (nwg >> 3) + (bid >> 3);
    const int mi  = swz & 63;            // MTOT/256 = 64 M-tiles
    const int ni  = swz >> 6;
    const long long bm = (long long)mi * 256;
    const long long bn = (long long)ni * 256;

    f32x4 acc[2][2][4][2] = {};          // [mh][nh][i][j] = 128 VGPRs

    auto STAGE = [&](int s) {
        const int kind = s & 3;
        const int slot = ((s >> 2) & 1) * 4 + kind;
        const int kt   = (s >> 2) * 64;
        const bf16* src = (kind & 1) ? B : A;
        const long long rbase = ((kind & 1) ? bn : bm) + (long long)(kind >> 1) * 128;
#pragma unroll
        for (int r = 0; r < 2; ++r) {
            const int c   = tid + r * 512;     // chunk id 0..1023
            const int row = c >> 3;            // 0..127
            const int qg  = (c & 7) ^ (row & 7);
            GLDS16(src + (rbase + row) * K + (kt + qg * 8),
                   (char*)lds[slot] + c * 16);
        }
    };

    // prologue: stage 7 half-tiles ahead (tile0 full + tile1 A0,B0,A1)
#pragma unroll
    for (int s = 0; s < 7; ++s) STAGE(s);
    asm volatile("s_waitcnt vmcnt(6)" ::: "memory");   // tile0 landed
    __builtin_amdgcn_s_barrier();
    asm volatile("" ::: "memory");
    __builtin_amdgcn_sched_barrier(0);

    for (int T = 0; T < NT; ++T) {
        const int bufb = (T & 1) * 4;
#pragma unroll
        for (int q = 0; q < 4; ++q) {
            const int mh = q >> 1, nh = q & 1;

            // --- ds-read this phase's register subtile (12 x b128) ---
            bf16x8 af[4][2], bfr[2][2];
#pragma unroll
            for (int i = 0; i < 4; ++i) {
                const int rl = wr * 64 + i * 16 + lrow;
                const bf16* base = &lds[bufb + mh * 2][rl * 64];
#pragma unroll
                for (int h = 0; h < 2; ++h)
                    af[i][h] = *(const bf16x8*)(base + ((h * 4 + quad) ^ (rl & 7)) * 8);
            }
#pragma unroll
            for (int j = 0; j < 2; ++j) {
                const int rl = wc * 32 + j * 16 + lrow;
                const bf16* base = &lds[bufb + nh * 2 + 1][rl * 64];
#pragma unroll
                for (int h = 0; h < 2; ++h)
                    bfr[j][h] = *(const bf16x8*)(base + ((h * 4 + quad) ^ (rl & 7)) * 8);
            }
            // all reads sampled before the barrier; stages issued after it
            // -> overwrite hazard is barrier-separated.
            asm volatile("s_waitcnt lgkmcnt(0)" ::: "memory");
            __builtin_amdgcn_sched_barrier(0);
            __builtin_amdgcn_s_barrier();
            asm volatile("" ::: "memory");
            __builtin_amdgcn_sched_barrier(0);

            // --- stage one half-tile, 7 phases ahead ---
            {
                const int s = 4 * T + q + 7;
                if (s < 4 * NT) STAGE(s);
            }

            // --- 16 MFMA: one C-quadrant x K=64 ---
            __builtin_amdgcn_s_setprio(1);
#pragma unroll
            for (int h = 0; h < 2; ++h)
#pragma unroll
                for (int i = 0; i < 4; ++i)
#pragma unroll
                    for (int j = 0; j < 2; ++j)
                        acc[mh][nh][i][j] = __builtin_amdgcn_mfma_f32_16x16x32_bf16(
                            af[i][h], bfr[j][h], acc[mh][nh][i][j], 0, 0, 0);
            __builtin_amdgcn_s_setprio(0);

            // counted vmcnt once per K-tile: keep 3 half-tiles in flight
            if (q == 3) {
                if (T < NT - 2)       asm volatile("s_waitcnt vmcnt(6)" ::: "memory");
                else if (T == NT - 2) asm volatile("s_waitcnt vmcnt(0)" ::: "memory");
            }
            __builtin_amdgcn_s_barrier();
            asm volatile("" ::: "memory");
            __builtin_amdgcn_sched_barrier(0);
        }
    }

    // epilogue: C/D layout col = lane&15, row = quad*4 + reg  [m89/m91]
#pragma unroll
    for (int nh = 0; nh < 2; ++nh)
#pragma unroll
        for (int j = 0; j < 2; ++j) {
            const long long gcol = bn + nh * 128 + wc * 32 + j * 16 + lrow;
            const float bv = bias[gcol];
#pragma unroll
            for (int mh = 0; mh < 2; ++mh)
#pragma unroll
                for (int i = 0; i < 4; ++i) {
                    const long long grow0 = bm + mh * 128 + wr * 64 + i * 16 + quad * 4;
#pragma unroll
                    for (int r = 0; r < 4; ++r)
                        C[(grow0 + r) * N + gcol] = (OutT)(acc[mh][nh][i][j][r] + bv);
                }
        }
}

// ---------------------------------------------------------------------------
// Causal depthwise conv1d (K=4, left pad 3) + bias + SiLU.
// X,Y: bf16 [b*S + s][c] row-major. conv_w/conv_b: fp32.
// ---------------------------------------------------------------------------
__global__ __launch_bounds__(256)
void conv_silu_kernel(const bf16* __restrict__ X, const float* __restrict__ cw,
                      const float* __restrict__ cb, bf16* __restrict__ Y) {
    const int gid = blockIdx.x * 256 + threadIdx.x;   // MTOT * 512 threads
    const int c0  = (gid & 511) << 3;                 // channel base (8/thread)
    const int bs  = gid >> 9;
    const int s   = bs & (SEQ - 1);

    float w[8][4];
#pragma unroll
    for (int j = 0; j < 8; ++j) {
        const float4 t = *(const float4*)(cw + (long long)(c0 + j) * 4);
        w[j][0] = t.x; w[j][1] = t.y; w[j][2] = t.z; w[j][3] = t.w;
    }
    float acc[8];
    {
        const float4 b0 = *(const float4*)(cb + c0);
        const float4 b1 = *(const float4*)(cb + c0 + 4);
        acc[0] = b0.x; acc[1] = b0.y; acc[2] = b0.z; acc[3] = b0.w;
        acc[4] = b1.x; acc[5] = b1.y; acc[6] = b1.z; acc[7] = b1.w;
    }
#pragma unroll
    for (int k = 0; k < 4; ++k) {
        const int ss = s - 3 + k;
        if (ss >= 0) {
            B8 x;
            x.v = *(const uint4*)(X + (long long)(bs - 3 + k) * CHANNELS + c0);
#pragma unroll
            for (int j = 0; j < 8; ++j) acc[j] += w[j][k] * (float)x.h[j];
        }
    }
    B8 o;
#pragma unroll
    for (int j = 0; j < 8; ++j) {
        const float v = acc[j];
        o.h[j] = (bf16)(v / (1.0f + __expf(-v)));
    }
    *(uint4*)(Y + (long long)bs * CHANNELS + c0) = o.v;
}

// ---------------------------------------------------------------------------
extern "C" void kernel_launch(void* const* d_in, const int* in_sizes, int n_in,
                              void* d_out, int out_size, void* d_ws, size_t ws_size,
                              hipStream_t stream) {
    const float* hs    = (const float*)d_in[0];  // [4,4096,2048]
    const float* w_in  = (const float*)d_in[1];  // [4096,2048]
    const float* b_in  = (const float*)d_in[2];  // [4096]
    const float* cw    = (const float*)d_in[3];  // [4096,1,4]
    const float* cb    = (const float*)d_in[4];  // [4096]
    const float* w_out = (const float*)d_in[5];  // [2048,4096]
    const float* b_out = (const float*)d_in[6];  // [2048]
    float* out = (float*)d_out;                  // [4,4096,2048] fp32

    // ws layout (peak 272 MiB). Y overlaps hs_b/w_in_b — both dead before
    // conv writes Y (stream-ordered).
    char* ws = (char*)d_ws;
    bf16* X       = (bf16*)(ws);                           // [  0,128M)
    bf16* Y       = (bf16*)(ws + ((size_t)128 << 20));     // [128,256M)
    bf16* hs_b    = (bf16*)(ws + ((size_t)128 << 20));     // [128,192M) dies pre-conv
    bf16* w_in_b  = (bf16*)(ws + ((size_t)192 << 20));     // [192,208M) dies pre-conv
    bf16* w_out_b = (bf16*)(ws + ((size_t)256 << 20));     // [256,272M)

    cast_f32_to_bf16<<<(MTOT * HIDDEN) / (8 * 256), 256, 0, stream>>>(hs, hs_b);
    cast_f32_to_bf16<<<(CHANNELS * HIDDEN) / (8 * 256), 256, 0, stream>>>(w_in, w_in_b);
    cast_f32_to_bf16<<<(HIDDEN * CHANNELS) / (8 * 256), 256, 0, stream>>>(w_out, w_out_b);

    // GEMM1: X = hs @ w_in^T + b_in   [16384 x 4096], K=2048
    gemm256_bt_bias<bf16, CHANNELS, HIDDEN>
        <<<(MTOT / 256) * (CHANNELS / 256), 512, 0, stream>>>(hs_b, w_in_b, b_in, X);

    // conv + silu: Y = silu(causal_conv(X) + cb)
    conv_silu_kernel<<<MTOT * (CHANNELS / 8) / 256, 256, 0, stream>>>(X, cw, cb, Y);

    // GEMM2: out = Y @ w_out^T + b_out   [16384 x 2048], K=4096  (fp32 out)
    gemm256_bt_bias<float, HIDDEN, CHANNELS>
        <<<(MTOT / 256) * (HIDDEN / 256), 512, 0, stream>>>(Y, w_out_b, b_out, out);
}

// Round 2
// 994.719 us; speedup vs baseline: 1.2451x; 1.1327x over previous
//
#include <hip/hip_runtime.h>
#include <hip/hip_bf16.h>
#include <stdint.h>

#define SEQ      4096
#define BATCH    4
#define HIDDEN   2048
#define CHANNELS 4096
#define MTOT     (BATCH*SEQ)   // 16384

typedef __bf16 bf16;
typedef __bf16 bf16x8 __attribute__((ext_vector_type(8)));
typedef float  f32x4  __attribute__((ext_vector_type(4)));

// async 16B global->LDS (wave-uniform base + lane*16 on LDS side)
#define GLDS16(g, l) __builtin_amdgcn_global_load_lds(                      \
    (const __attribute__((address_space(1))) void*)(g),                     \
    (__attribute__((address_space(3))) void*)(l), 16, 0, 0)

union B8 { uint4 v; bf16 h[8]; };

// barrier WITHOUT implicit waitcnt drain; sched_barriers pin code motion
#define SBAR() do {                                   \
    __builtin_amdgcn_sched_barrier(0);                \
    __builtin_amdgcn_s_barrier();                     \
    asm volatile("" ::: "memory");                    \
    __builtin_amdgcn_sched_barrier(0); } while (0)
#define LGKM0() do {                                  \
    asm volatile("s_waitcnt lgkmcnt(0)" ::: "memory");\
    __builtin_amdgcn_sched_barrier(0); } while (0)

// ---------------------------------------------------------------------------
// fp32 -> bf16 cast, 8 elems/thread
// ---------------------------------------------------------------------------
__global__ __launch_bounds__(256)
void cast_f32_to_bf16(const float* __restrict__ in, bf16* __restrict__ out) {
    const long long i = (long long)blockIdx.x * 256 + threadIdx.x;
    const float4 a = ((const float4*)in)[2 * i];
    const float4 b = ((const float4*)in)[2 * i + 1];
    B8 o;
    o.h[0] = (bf16)a.x; o.h[1] = (bf16)a.y; o.h[2] = (bf16)a.z; o.h[3] = (bf16)a.w;
    o.h[4] = (bf16)b.x; o.h[5] = (bf16)b.y; o.h[6] = (bf16)b.z; o.h[7] = (bf16)b.w;
    *(uint4*)(out + 8 * i) = o.v;
}

// ---------------------------------------------------------------------------
// NT GEMM, 256x256 tile, BK=64, 512 thr (8 waves: 2M x 4N), 8-slot pipeline.
// C[m][n] = sum_k A[m][k]*B[n][k] + bias[n].
//
// LDS: 8 half-tile slots of 16 KB (128 rows x 64 bf16); stage s -> slot s%8,
// kind s&3: 0=A[0,128) 1=B[0,128) 2=A[128,256) 3=B[128,256), tile s>>2.
// Chunk swizzle (proven 0-conflict): LDS 16B slot q holds global chunk
// q^(row&7); GLDS dest lane-linear, source pre-swizzled.
//
// Per K-tile, snake phase order (mh,nh) = (0,0),(0,1),(1,1),(1,0) with
// register reuse: A-frags held across each nh pair, B0/B1 frags held for
// the whole K-tile -> 24 ds_read_b128 per wave per K-tile (12,4,8,0).
// Phase = [issue reads][issue 1 stage, 6 phases ahead][barrier]
//         [lgkmcnt(0)][16 MFMA][q==3: counted vmcnt][barrier]
// lgkm wait AFTER the barrier -> waves enter MFMA as their own reads land,
// LDS queue drains under other waves' MFMA (the R1 version drained before
// the barrier -> full serialization, MfmaUtil 34%).
// Hazard: stage at phase P overwrites content last READ at phase <= P-2,
// drained at that phase's lgkm0, >=2 barriers before the write. vmcnt(4)
// once per K-tile (2 stages in flight) guarantees tile T+1 staged.
// ---------------------------------------------------------------------------
template <typename OutT, int N, int K>
__global__ __launch_bounds__(512, 2)
void gemm256_bt_bias(const bf16* __restrict__ A, const bf16* __restrict__ B,
                     const float* __restrict__ bias, OutT* __restrict__ C) {
    constexpr int NT    = K / 64;        // K-tiles
    constexpr int NTILE = N / 256;       // N-tiles (power of 2)
    __shared__ bf16 lds[8][128 * 64];    // 128 KiB

    const int tid  = threadIdx.x;
    const int lane = tid & 63;
    const int wave = tid >> 6;
    const int wr   = wave >> 2;          // 0..1
    const int wc   = wave & 3;           // 0..3
    const int quad = lane >> 4;          // 0..3
    const int lrow = lane & 15;          // 0..15

    // XCD-chunked bijective swizzle (nwg % 8 == 0). N fastest within a
    // chunk: concurrent working set = few A panels + all B (L3-resident);
    // A streamed once chip-wide. (M-fastest made every XCD stream all of
    // A: FETCH 540 MB.)
    const int nwg = gridDim.x;
    const int bid = blockIdx.x;
    const int swz = (bid & 7) * (nwg >> 3) + (bid >> 3);
    const int ni  = swz % NTILE;
    const int mi  = swz / NTILE;
    const long long bm = (long long)mi * 256;
    const long long bn = (long long)ni * 256;

    f32x4 acc[2][2][4][2] = {};          // [mh][nh][i][j] = 128 regs
    bf16x8 a[4][2], b0[2][2], b1[2][2];  // 64 regs peak

    auto STAGE = [&](int s) {
        const int kind = s & 3;
        const int slot = s & 7;
        const int kt   = (s >> 2) * 64;
        const bf16* src = (kind & 1) ? B : A;
        const long long rbase = ((kind & 1) ? bn : bm) + (long long)(kind >> 1) * 128;
#pragma unroll
        for (int r = 0; r < 2; ++r) {
            const int c   = tid + r * 512;     // chunk id 0..1023
            const int row = c >> 3;            // 0..127
            const int qg  = (c & 7) ^ (row & 7);
            GLDS16(src + (rbase + row) * K + (kt + qg * 8),
                   (char*)lds[slot] + c * 16);
        }
    };
    auto READ_A = [&](bf16x8 (&dst)[4][2], int bufb, int mh) {
#pragma unroll
        for (int i = 0; i < 4; ++i) {
            const int rl = wr * 64 + i * 16 + lrow;
            const bf16* base = &lds[bufb + mh * 2][rl * 64];
#pragma unroll
            for (int h = 0; h < 2; ++h)
                dst[i][h] = *(const bf16x8*)(base + ((h * 4 + quad) ^ (rl & 7)) * 8);
        }
    };
    auto READ_B = [&](bf16x8 (&dst)[2][2], int bufb, int nh) {
#pragma unroll
        for (int j = 0; j < 2; ++j) {
            const int rl = wc * 32 + j * 16 + lrow;
            const bf16* base = &lds[bufb + nh * 2 + 1][rl * 64];
#pragma unroll
            for (int h = 0; h < 2; ++h)
                dst[j][h] = *(const bf16x8*)(base + ((h * 4 + quad) ^ (rl & 7)) * 8);
        }
    };
    auto MFMAQ = [&](int mh, int nh, bf16x8 (&Af)[4][2], bf16x8 (&Bf)[2][2]) {
        __builtin_amdgcn_s_setprio(1);
#pragma unroll
        for (int h = 0; h < 2; ++h)
#pragma unroll
            for (int i = 0; i < 4; ++i)
#pragma unroll
                for (int j = 0; j < 2; ++j)
                    acc[mh][nh][i][j] = __builtin_amdgcn_mfma_f32_16x16x32_bf16(
                        Af[i][h], Bf[j][h], acc[mh][nh][i][j], 0, 0, 0);
        __builtin_amdgcn_s_setprio(0);
    };

    // prologue: stage s=0..5 (tile0 full + tile1 A-lo,B-lo); tile0 landed
#pragma unroll
    for (int s = 0; s < 6; ++s) STAGE(s);
    asm volatile("s_waitcnt vmcnt(4)" ::: "memory");
    SBAR();

    for (int T = 0; T < NT; ++T) {
        const int bufb = (T & 1) * 4;
        const int P0   = 4 * T;

        // ---- phase 0: (0,0) — read A0 (8) + B0 (4) ----
        READ_A(a, bufb, 0);
        READ_B(b0, bufb, 0);
        if (P0 + 6 < 4 * NT) STAGE(P0 + 6);
        SBAR(); LGKM0();
        MFMAQ(0, 0, a, b0);
        SBAR();

        // ---- phase 1: (0,1) — read B1 (4), A held ----
        READ_B(b1, bufb, 1);
        if (P0 + 7 < 4 * NT) STAGE(P0 + 7);
        SBAR(); LGKM0();
        MFMAQ(0, 1, a, b1);
        SBAR();

        // ---- phase 2: (1,1) — read A1 (8), B1 held ----
        READ_A(a, bufb, 1);
        if (P0 + 8 < 4 * NT) STAGE(P0 + 8);
        SBAR(); LGKM0();
        MFMAQ(1, 1, a, b1);
        SBAR();

        // ---- phase 3: (1,0) — no reads, A1 + B0 held ----
        if (P0 + 9 < 4 * NT) STAGE(P0 + 9);
        SBAR();
        MFMAQ(1, 0, a, b0);
        if (T < NT - 2)       asm volatile("s_waitcnt vmcnt(4)" ::: "memory");
        else if (T == NT - 2) asm volatile("s_waitcnt vmcnt(0)" ::: "memory");
        SBAR();
    }

    // epilogue: C/D layout col = lane&15, row = quad*4 + reg  [m89/m91]
#pragma unroll
    for (int nh = 0; nh < 2; ++nh)
#pragma unroll
        for (int j = 0; j < 2; ++j) {
            const long long gcol = bn + nh * 128 + wc * 32 + j * 16 + lrow;
            const float bv = bias[gcol];
#pragma unroll
            for (int mh = 0; mh < 2; ++mh)
#pragma unroll
                for (int i = 0; i < 4; ++i) {
                    const long long grow0 = bm + mh * 128 + wr * 64 + i * 16 + quad * 4;
#pragma unroll
                    for (int r = 0; r < 4; ++r)
                        C[(grow0 + r) * N + gcol] = (OutT)(acc[mh][nh][i][j][r] + bv);
                }
        }
}

// ---------------------------------------------------------------------------
// Causal depthwise conv1d (K=4, left pad 3) + bias + SiLU.
// X,Y: bf16 [b*S + s][c] row-major. conv_w/conv_b: fp32.
// ---------------------------------------------------------------------------
__global__ __launch_bounds__(256)
void conv_silu_kernel(const bf16* __restrict__ X, const float* __restrict__ cw,
                      const float* __restrict__ cb, bf16* __restrict__ Y) {
    const int gid = blockIdx.x * 256 + threadIdx.x;   // MTOT * 512 threads
    const int c0  = (gid & 511) << 3;                 // channel base (8/thread)
    const int bs  = gid >> 9;
    const int s   = bs & (SEQ - 1);

    float w[8][4];
#pragma unroll
    for (int j = 0; j < 8; ++j) {
        const float4 t = *(const float4*)(cw + (long long)(c0 + j) * 4);
        w[j][0] = t.x; w[j][1] = t.y; w[j][2] = t.z; w[j][3] = t.w;
    }
    float acc[8];
    {
        const float4 b0 = *(const float4*)(cb + c0);
        const float4 b1 = *(const float4*)(cb + c0 + 4);
        acc[0] = b0.x; acc[1] = b0.y; acc[2] = b0.z; acc[3] = b0.w;
        acc[4] = b1.x; acc[5] = b1.y; acc[6] = b1.z; acc[7] = b1.w;
    }
#pragma unroll
    for (int k = 0; k < 4; ++k) {
        const int ss = s - 3 + k;
        if (ss >= 0) {
            B8 x;
            x.v = *(const uint4*)(X + (long long)(bs - 3 + k) * CHANNELS + c0);
#pragma unroll
            for (int j = 0; j < 8; ++j) acc[j] += w[j][k] * (float)x.h[j];
        }
    }
    B8 o;
#pragma unroll
    for (int j = 0; j < 8; ++j) {
        const float v = acc[j];
        o.h[j] = (bf16)(v / (1.0f + __expf(-v)));
    }
    *(uint4*)(Y + (long long)bs * CHANNELS + c0) = o.v;
}

// ---------------------------------------------------------------------------
extern "C" void kernel_launch(void* const* d_in, const int* in_sizes, int n_in,
                              void* d_out, int out_size, void* d_ws, size_t ws_size,
                              hipStream_t stream) {
    const float* hs    = (const float*)d_in[0];  // [4,4096,2048]
    const float* w_in  = (const float*)d_in[1];  // [4096,2048]
    const float* b_in  = (const float*)d_in[2];  // [4096]
    const float* cw    = (const float*)d_in[3];  // [4096,1,4]
    const float* cb    = (const float*)d_in[4];  // [4096]
    const float* w_out = (const float*)d_in[5];  // [2048,4096]
    const float* b_out = (const float*)d_in[6];  // [2048]
    float* out = (float*)d_out;                  // [4,4096,2048] fp32

    // ws layout (peak 272 MiB). Y overlaps hs_b/w_in_b — both dead before
    // conv writes Y (stream-ordered).
    char* ws = (char*)d_ws;
    bf16* X       = (bf16*)(ws);                           // [  0,128M)
    bf16* Y       = (bf16*)(ws + ((size_t)128 << 20));     // [128,256M)
    bf16* hs_b    = (bf16*)(ws + ((size_t)128 << 20));     // [128,192M) dies pre-conv
    bf16* w_in_b  = (bf16*)(ws + ((size_t)192 << 20));     // [192,208M) dies pre-conv
    bf16* w_out_b = (bf16*)(ws + ((size_t)256 << 20));     // [256,272M)

    cast_f32_to_bf16<<<(MTOT * HIDDEN) / (8 * 256), 256, 0, stream>>>(hs, hs_b);
    cast_f32_to_bf16<<<(CHANNELS * HIDDEN) / (8 * 256), 256, 0, stream>>>(w_in, w_in_b);
    cast_f32_to_bf16<<<(HIDDEN * CHANNELS) / (8 * 256), 256, 0, stream>>>(w_out, w_out_b);

    // GEMM1: X = hs @ w_in^T + b_in   [16384 x 4096], K=2048
    gemm256_bt_bias<bf16, CHANNELS, HIDDEN>
        <<<(MTOT / 256) * (CHANNELS / 256), 512, 0, stream>>>(hs_b, w_in_b, b_in, X);

    // conv + silu: Y = silu(causal_conv(X) + cb)
    conv_silu_kernel<<<MTOT * (CHANNELS / 8) / 256, 256, 0, stream>>>(X, cw, cb, Y);

    // GEMM2: out = Y @ w_out^T + b_out   [16384 x 2048], K=4096  (fp32 out)
    gemm256_bt_bias<float, HIDDEN, CHANNELS>
        <<<(MTOT / 256) * (HIDDEN / 256), 512, 0, stream>>>(Y, w_out_b, b_out, out);
}

// Round 3
// 795.239 us; speedup vs baseline: 1.5575x; 1.2508x over previous
//
#include <hip/hip_runtime.h>
#include <hip/hip_bf16.h>
#include <stdint.h>

#define SEQ      4096
#define BATCH    4
#define HIDDEN   2048
#define CHANNELS 4096
#define MTOT     (BATCH*SEQ)   // 16384

typedef __bf16 bf16;
typedef __bf16 bf16x8 __attribute__((ext_vector_type(8)));
typedef float  f32x4  __attribute__((ext_vector_type(4)));

// async 16B global->LDS (wave-uniform base + lane*16 on LDS side)
#define GLDS16(g, l) __builtin_amdgcn_global_load_lds(                      \
    (const __attribute__((address_space(1))) void*)(g),                     \
    (__attribute__((address_space(3))) void*)(l), 16, 0, 0)

union B8 { uint4 v; bf16 h[8]; };

// barrier WITHOUT implicit waitcnt drain; sched_barriers pin code motion
#define SBAR() do {                                   \
    __builtin_amdgcn_sched_barrier(0);                \
    __builtin_amdgcn_s_barrier();                     \
    asm volatile("" ::: "memory");                    \
    __builtin_amdgcn_sched_barrier(0); } while (0)
#define LGKM0() do {                                  \
    asm volatile("s_waitcnt lgkmcnt(0)" ::: "memory");\
    __builtin_amdgcn_sched_barrier(0); } while (0)

// ---------------------------------------------------------------------------
// fp32 -> bf16 cast, 8 elems/thread
// ---------------------------------------------------------------------------
__global__ __launch_bounds__(256)
void cast_f32_to_bf16(const float* __restrict__ in, bf16* __restrict__ out) {
    const long long i = (long long)blockIdx.x * 256 + threadIdx.x;
    const float4 a = ((const float4*)in)[2 * i];
    const float4 b = ((const float4*)in)[2 * i + 1];
    B8 o;
    o.h[0] = (bf16)a.x; o.h[1] = (bf16)a.y; o.h[2] = (bf16)a.z; o.h[3] = (bf16)a.w;
    o.h[4] = (bf16)b.x; o.h[5] = (bf16)b.y; o.h[6] = (bf16)b.z; o.h[7] = (bf16)b.w;
    *(uint4*)(out + 8 * i) = o.v;
}

// ---------------------------------------------------------------------------
// NT GEMM, 256x256 tile, BK=64, 512 thr (8 waves: 2M x 4N), 8-slot pipeline.
// (unchanged from R2 — see comments there; GEMMs now ~<=268 us each)
// ---------------------------------------------------------------------------
template <typename OutT, int N, int K>
__global__ __launch_bounds__(512, 2)
void gemm256_bt_bias(const bf16* __restrict__ A, const bf16* __restrict__ B,
                     const float* __restrict__ bias, OutT* __restrict__ C) {
    constexpr int NT    = K / 64;        // K-tiles
    constexpr int NTILE = N / 256;       // N-tiles (power of 2)
    __shared__ bf16 lds[8][128 * 64];    // 128 KiB

    const int tid  = threadIdx.x;
    const int lane = tid & 63;
    const int wave = tid >> 6;
    const int wr   = wave >> 2;          // 0..1
    const int wc   = wave & 3;           // 0..3
    const int quad = lane >> 4;          // 0..3
    const int lrow = lane & 15;          // 0..15

    // XCD-chunked bijective swizzle (nwg % 8 == 0), N fastest within chunk.
    const int nwg = gridDim.x;
    const int bid = blockIdx.x;
    const int swz = (bid & 7) * (nwg >> 3) + (bid >> 3);
    const int ni  = swz % NTILE;
    const int mi  = swz / NTILE;
    const long long bm = (long long)mi * 256;
    const long long bn = (long long)ni * 256;

    f32x4 acc[2][2][4][2] = {};          // [mh][nh][i][j] = 128 regs
    bf16x8 a[4][2], b0[2][2], b1[2][2];  // 64 regs peak

    auto STAGE = [&](int s) {
        const int kind = s & 3;
        const int slot = s & 7;
        const int kt   = (s >> 2) * 64;
        const bf16* src = (kind & 1) ? B : A;
        const long long rbase = ((kind & 1) ? bn : bm) + (long long)(kind >> 1) * 128;
#pragma unroll
        for (int r = 0; r < 2; ++r) {
            const int c   = tid + r * 512;     // chunk id 0..1023
            const int row = c >> 3;            // 0..127
            const int qg  = (c & 7) ^ (row & 7);
            GLDS16(src + (rbase + row) * K + (kt + qg * 8),
                   (char*)lds[slot] + c * 16);
        }
    };
    auto READ_A = [&](bf16x8 (&dst)[4][2], int bufb, int mh) {
#pragma unroll
        for (int i = 0; i < 4; ++i) {
            const int rl = wr * 64 + i * 16 + lrow;
            const bf16* base = &lds[bufb + mh * 2][rl * 64];
#pragma unroll
            for (int h = 0; h < 2; ++h)
                dst[i][h] = *(const bf16x8*)(base + ((h * 4 + quad) ^ (rl & 7)) * 8);
        }
    };
    auto READ_B = [&](bf16x8 (&dst)[2][2], int bufb, int nh) {
#pragma unroll
        for (int j = 0; j < 2; ++j) {
            const int rl = wc * 32 + j * 16 + lrow;
            const bf16* base = &lds[bufb + nh * 2 + 1][rl * 64];
#pragma unroll
            for (int h = 0; h < 2; ++h)
                dst[j][h] = *(const bf16x8*)(base + ((h * 4 + quad) ^ (rl & 7)) * 8);
        }
    };
    auto MFMAQ = [&](int mh, int nh, bf16x8 (&Af)[4][2], bf16x8 (&Bf)[2][2]) {
        __builtin_amdgcn_s_setprio(1);
#pragma unroll
        for (int h = 0; h < 2; ++h)
#pragma unroll
            for (int i = 0; i < 4; ++i)
#pragma unroll
                for (int j = 0; j < 2; ++j)
                    acc[mh][nh][i][j] = __builtin_amdgcn_mfma_f32_16x16x32_bf16(
                        Af[i][h], Bf[j][h], acc[mh][nh][i][j], 0, 0, 0);
        __builtin_amdgcn_s_setprio(0);
    };

    // prologue: stage s=0..5 (tile0 full + tile1 A-lo,B-lo); tile0 landed
#pragma unroll
    for (int s = 0; s < 6; ++s) STAGE(s);
    asm volatile("s_waitcnt vmcnt(4)" ::: "memory");
    SBAR();

    for (int T = 0; T < NT; ++T) {
        const int bufb = (T & 1) * 4;
        const int P0   = 4 * T;

        // ---- phase 0: (0,0) — read A0 (8) + B0 (4) ----
        READ_A(a, bufb, 0);
        READ_B(b0, bufb, 0);
        if (P0 + 6 < 4 * NT) STAGE(P0 + 6);
        SBAR(); LGKM0();
        MFMAQ(0, 0, a, b0);
        SBAR();

        // ---- phase 1: (0,1) — read B1 (4), A held ----
        READ_B(b1, bufb, 1);
        if (P0 + 7 < 4 * NT) STAGE(P0 + 7);
        SBAR(); LGKM0();
        MFMAQ(0, 1, a, b1);
        SBAR();

        // ---- phase 2: (1,1) — read A1 (8), B1 held ----
        READ_A(a, bufb, 1);
        if (P0 + 8 < 4 * NT) STAGE(P0 + 8);
        SBAR(); LGKM0();
        MFMAQ(1, 1, a, b1);
        SBAR();

        // ---- phase 3: (1,0) — no reads, A1 + B0 held ----
        if (P0 + 9 < 4 * NT) STAGE(P0 + 9);
        SBAR();
        MFMAQ(1, 0, a, b0);
        if (T < NT - 2)       asm volatile("s_waitcnt vmcnt(4)" ::: "memory");
        else if (T == NT - 2) asm volatile("s_waitcnt vmcnt(0)" ::: "memory");
        SBAR();
    }

    // epilogue: C/D layout col = lane&15, row = quad*4 + reg  [m89/m91]
#pragma unroll
    for (int nh = 0; nh < 2; ++nh)
#pragma unroll
        for (int j = 0; j < 2; ++j) {
            const long long gcol = bn + nh * 128 + wc * 32 + j * 16 + lrow;
            const float bv = bias[gcol];
#pragma unroll
            for (int mh = 0; mh < 2; ++mh)
#pragma unroll
                for (int i = 0; i < 4; ++i) {
                    const long long grow0 = bm + mh * 128 + wr * 64 + i * 16 + quad * 4;
#pragma unroll
                    for (int r = 0; r < 4; ++r)
                        C[(grow0 + r) * N + gcol] = (OutT)(acc[mh][nh][i][j][r] + bv);
                }
        }
}

// ---------------------------------------------------------------------------
// Causal depthwise conv1d (K=4, left pad 3) + bias + SiLU.  v2:
// each thread owns 8 channels x 8 consecutive seq positions. 11 X rows
// loaded into regs (full MLP), weights loaded ONCE per 8 outputs (the v1
// per-output divergent weight loads were the bottleneck: 120 VMEM instrs
// per 16B output, 1.5 TB/s). All indexing static after unroll (rule #20).
// FMA order per output identical to v1 -> bit-identical results.
// ---------------------------------------------------------------------------
__global__ __launch_bounds__(256)
void conv_silu_kernel(const bf16* __restrict__ X, const float* __restrict__ cw,
                      const float* __restrict__ cb, bf16* __restrict__ Y) {
    const int gid = blockIdx.x * 256 + threadIdx.x;   // MTOT/8 * 512 threads
    const int c0  = (gid & 511) << 3;                 // channel base (8/thread)
    const long long bs0 = (long long)(gid >> 9) * 8;  // first output row
    const int s0  = (int)(bs0 & (SEQ - 1));           // pos within batch (wave-uniform)

    float w[8][4];
#pragma unroll
    for (int j = 0; j < 8; ++j) {
        const float4 t = *(const float4*)(cw + (long long)(c0 + j) * 4);
        w[j][0] = t.x; w[j][1] = t.y; w[j][2] = t.z; w[j][3] = t.w;
    }
    float bv[8];
    {
        const float4 b0 = *(const float4*)(cb + c0);
        const float4 b1 = *(const float4*)(cb + c0 + 4);
        bv[0] = b0.x; bv[1] = b0.y; bv[2] = b0.z; bv[3] = b0.w;
        bv[4] = b1.x; bv[5] = b1.y; bv[6] = b1.z; bv[7] = b1.w;
    }

    // rows[t] = X row (bs0 + t - 3); t=0..2 may cross batch start -> zero
    B8 rows[11];
#pragma unroll
    for (int t = 0; t < 11; ++t) {
        if (s0 + t - 3 >= 0)
            rows[t].v = *(const uint4*)(X + (bs0 + t - 3) * CHANNELS + c0);
        else
            rows[t].v = uint4{0, 0, 0, 0};
    }

#pragma unroll
    for (int t = 0; t < 8; ++t) {          // output row bs0 + t
        B8 o;
#pragma unroll
        for (int j = 0; j < 8; ++j) {
            float a = bv[j];
            a += w[j][0] * (float)rows[t + 0].h[j];
            a += w[j][1] * (float)rows[t + 1].h[j];
            a += w[j][2] * (float)rows[t + 2].h[j];
            a += w[j][3] * (float)rows[t + 3].h[j];
            o.h[j] = (bf16)(a / (1.0f + __expf(-a)));
        }
        *(uint4*)(Y + (bs0 + t) * CHANNELS + c0) = o.v;
    }
}

// ---------------------------------------------------------------------------
extern "C" void kernel_launch(void* const* d_in, const int* in_sizes, int n_in,
                              void* d_out, int out_size, void* d_ws, size_t ws_size,
                              hipStream_t stream) {
    const float* hs    = (const float*)d_in[0];  // [4,4096,2048]
    const float* w_in  = (const float*)d_in[1];  // [4096,2048]
    const float* b_in  = (const float*)d_in[2];  // [4096]
    const float* cw    = (const float*)d_in[3];  // [4096,1,4]
    const float* cb    = (const float*)d_in[4];  // [4096]
    const float* w_out = (const float*)d_in[5];  // [2048,4096]
    const float* b_out = (const float*)d_in[6];  // [2048]
    float* out = (float*)d_out;                  // [4,4096,2048] fp32

    // ws layout (peak 272 MiB). Y overlaps hs_b/w_in_b — both dead before
    // conv writes Y (stream-ordered).
    char* ws = (char*)d_ws;
    bf16* X       = (bf16*)(ws);                           // [  0,128M)
    bf16* Y       = (bf16*)(ws + ((size_t)128 << 20));     // [128,256M)
    bf16* hs_b    = (bf16*)(ws + ((size_t)128 << 20));     // [128,192M) dies pre-conv
    bf16* w_in_b  = (bf16*)(ws + ((size_t)192 << 20));     // [192,208M) dies pre-conv
    bf16* w_out_b = (bf16*)(ws + ((size_t)256 << 20));     // [256,272M)

    cast_f32_to_bf16<<<(MTOT * HIDDEN) / (8 * 256), 256, 0, stream>>>(hs, hs_b);
    cast_f32_to_bf16<<<(CHANNELS * HIDDEN) / (8 * 256), 256, 0, stream>>>(w_in, w_in_b);
    cast_f32_to_bf16<<<(HIDDEN * CHANNELS) / (8 * 256), 256, 0, stream>>>(w_out, w_out_b);

    // GEMM1: X = hs @ w_in^T + b_in   [16384 x 4096], K=2048
    gemm256_bt_bias<bf16, CHANNELS, HIDDEN>
        <<<(MTOT / 256) * (CHANNELS / 256), 512, 0, stream>>>(hs_b, w_in_b, b_in, X);

    // conv + silu: Y = silu(causal_conv(X) + cb), 8 seq positions / thread
    conv_silu_kernel<<<(MTOT / 8) * (CHANNELS / 8) / 256, 256, 0, stream>>>(X, cw, cb, Y);

    // GEMM2: out = Y @ w_out^T + b_out   [16384 x 2048], K=4096  (fp32 out)
    gemm256_bt_bias<float, HIDDEN, CHANNELS>
        <<<(MTOT / 256) * (HIDDEN / 256), 512, 0, stream>>>(Y, w_out_b, b_out, out);
}